// Round 8
// baseline (889.567 us; speedup 1.0000x reference)
//
#include <hip/hip_runtime.h>
#include <hip/hip_bf16.h>

constexpr int TT = 512, BB = 2048, NOUT = 8;
constexpr size_t DSTRIDE = (size_t)BB * TT * 24;   // bf16 elems per dir region

typedef __attribute__((ext_vector_type(8))) short bf16x8;
typedef __attribute__((ext_vector_type(4))) float f32x4;
typedef __attribute__((ext_vector_type(2))) float f32x2;

__device__ __forceinline__ float sigm(float x) {
    return 1.f / (1.f + exp2f(x * -1.4426950408889634f));
}
__device__ __forceinline__ float tanh_(float x) {
    return 1.f - 2.f / (exp2f(x * 2.8853900817779268f) + 1.f);
}
__device__ __forceinline__ unsigned short f2bf(float x) {
    __hip_bfloat16 h = __float2bfloat16(x);
    unsigned short s;
    __builtin_memcpy(&s, &h, 2);
    return s;
}
__device__ __forceinline__ void wbar() { __builtin_amdgcn_wave_barrier(); }

// Wave-autonomous BiGRU layer; input gates via MFMA (bias folded into acc
// init), hidden matvec via v_pk_fma_f32 (W_hh as f32 pairs in 72 VGPRs, h
// broadcast as f32 through per-wave LDS). Steady state relies on the LDS
// pipe's in-order execution of one wave's DS ops (write->read needs no
// lgkmcnt fence; data waits are compiler-inserted). A-fragments software-
// pipelined one group ahead. block = 256 = 4 waves; wave owns 2 batch elems.
template <bool L0>
__global__ __launch_bounds__(256) void gru_mfma(
    const void* __restrict__ in_,        // L0: x [B][T][32] f32; else region0 (region1 at +DSTRIDE)
    const float* __restrict__ fmean, const float* __restrict__ fstd,
    const float* __restrict__ wih_g, const float* __restrict__ whh_g,
    const float* __restrict__ bih_g, const float* __restrict__ bhh_g,
    __hip_bfloat16* __restrict__ outbuf, float* __restrict__ lastbuf,
    int lastOnly)
{
    constexpr int KIN = L0 ? 32 : 46;

    __shared__ __align__(16) short  wih_lds[80 * 72];     // B^T bf16, stride 72
    __shared__ __align__(16) float  whh_s[80 * 24];       // W_hh f32
    __shared__ __align__(16) float  xg_s[4][16 * 84];     // per-wave D tile
    __shared__ __align__(16) float  hist_s[4 * 9 * 2 * 24];  // h history f32
    __shared__ float bih_s[80], bhh_s[80];
    __shared__ __align__(16) float an_s[32], cn_s[32];

    const int tid = threadIdx.x, wv = tid >> 6, lane = tid & 63;
    const int bl = lane >> 5, u = lane & 31;
    const int m  = lane & 15, kg = lane >> 4;             // MFMA lane coords
    const int dir = blockIdx.y;
    const int bg  = blockIdx.x * 8 + wv * 2 + bl;

    const float* wih_d = wih_g + dir * 69 * KIN;
    const float* whh_d = whh_g + dir * 69 * 23;

    // ---- stage W_ih as bf16 B^T [80][72], col-remapped ----
    for (int idx = tid; idx < 80 * 72; idx += 256) {
        int n = idx / 72, k = idx - n * 72;
        float v = 0.f;
        if (n < 69 && k < 64) {
            if constexpr (L0) {
                if (k < 32) v = wih_d[n * 32 + k];
            } else {
                if (k < 23) v = wih_d[n * 46 + k];                      // fwd
                else if (k >= 24 && k < 47) v = wih_d[n * 46 + k - 1];  // bwd
            }
        }
        wih_lds[idx] = (short)f2bf(v);
    }
    for (int idx = tid; idx < 80 * 24; idx += 256) {
        int j = idx / 24, k = idx - j * 24;
        whh_s[idx] = (j < 69 && k < 23) ? whh_d[j * 23 + k] : 0.f;
    }
    for (int idx = tid; idx < 80; idx += 256) {
        bih_s[idx] = (idx < 69) ? bih_g[dir * 69 + idx] : 0.f;
        bhh_s[idx] = (idx < 69) ? bhh_g[dir * 69 + idx] : 0.f;
    }
    for (int idx = tid; idx < 4 * 9 * 2 * 24; idx += 256) hist_s[idx] = 0.f;
    if (L0 && tid < 32) {
        float sd = fstd[tid];
        float sa = (sd == 0.f) ? 1.f : sd;        // std==0 -> 1
        float a  = (sa == 1.f) ? 0.f : 1.f / sa;  // adjusted std==1 -> zero
        an_s[tid] = a;
        cn_s[tid] = -fmean[tid] * a;
    }
    __syncthreads();   // only block-wide barrier

    // ---- per-lane W_hh rows (u, 23+u, 46+u) as f32 pairs -> 72 VGPRs ----
    f32x2 wrp[3][12];
    float bh[3];
    #pragma unroll
    for (int r = 0; r < 3; ++r) {
        int row = r * 23 + u;   // <= 77 < 80
        #pragma unroll
        for (int k = 0; k < 12; ++k)
            wrp[r][k] = *(const f32x2*)&whh_s[row * 24 + 2 * k];
        bh[r] = bhh_s[row];
    }
    // b_ih folded into MFMA acc init: per-lane bias for D col n = t*16+m
    float bi5[5];
    #pragma unroll
    for (int t = 0; t < 5; ++t) bi5[t] = bih_s[t * 16 + m];

    float an8[L0 ? 8 : 1], cn8[L0 ? 8 : 1];
    if constexpr (L0) {
        #pragma unroll
        for (int j = 0; j < 8; ++j) {
            an8[j] = an_s[kg * 8 + j];
            cn8[j] = cn_s[kg * 8 + j];
        }
    }

    float* xw = &xg_s[wv][0];
    float* hw = &hist_s[wv * 9 * 2 * 24];
    const int ngroups = (lastOnly && dir == 1) ? 1 : 64;
    float hold = 0.f;

    // ---- store-phase lane constants (hoisted: div by 12 done once) ----
    int sarr[3], cparr[3], ldsoff[3];
    {
        int idx = lane & 31;
        #pragma unroll
        for (int c = 0; c < 3; ++c) {
            int p = idx + 32 * c;             // 0..95
            sarr[c]  = p / 12;
            cparr[c] = p - 12 * sarr[c];
            ldsoff[c] = ((sarr[c] + 1) * 2 + bl) * 24 + 2 * cparr[c];
        }
    }
    unsigned short* dstbase = nullptr;
    if (!lastOnly)
        dstbase = (unsigned short*)outbuf + dir * DSTRIDE + (size_t)bg * TT * 24;

    // A-row coords: m = bl_a*8 + tl
    const int bl_a = m >> 3, tl = m & 7;
    const int b_a  = blockIdx.x * 8 + wv * 2 + bl_a;

    const unsigned short* r0 = (const unsigned short*)in_;
    const unsigned short* r1 = r0 + DSTRIDE;

    // ---- prefetch A-fragment raw data for group 0 ----
    float4 xraw0, xraw1;                 // L0 raw x
    bf16x8 a0r, a1r;                     // !L0 bf16 frags
    {
        const int tg_a = dir ? (511 - tl) : tl;
        if constexpr (L0) {
            const float* xr = (const float*)in_ +
                              ((size_t)b_a * TT + tg_a) * 32 + kg * 8;
            xraw0 = *(const float4*)xr;
            xraw1 = *(const float4*)(xr + 4);
        } else {
            size_t rowoff = ((size_t)b_a * TT + tg_a) * 24;
            const unsigned short* p0 =
                (kg < 3) ? (r0 + rowoff + 8 * kg) : (r1 + rowoff);
            const unsigned short* p1 =
                (kg == 0) ? (r1 + rowoff + 8) : (r1 + rowoff + 16);
            a0r = *(const bf16x8*)p0;
            a1r = *(const bf16x8*)p1;
        }
    }

    for (int g = 0; g < ngroups; ++g) {
        // ---- build A-frags from prefetched raw; acc init = bias ----
        f32x4 acc[5];
        #pragma unroll
        for (int t = 0; t < 5; ++t)
            acc[t] = (f32x4){bi5[t], bi5[t], bi5[t], bi5[t]};

        bf16x8 afr, a0u, a1u;
        if constexpr (L0) {
            float xv[8] = {xraw0.x, xraw0.y, xraw0.z, xraw0.w,
                           xraw1.x, xraw1.y, xraw1.z, xraw1.w};
            #pragma unroll
            for (int j = 0; j < 8; ++j)
                afr[j] = (short)f2bf(xv[j] * an8[j] + cn8[j]);
        } else {
            a0u = a0r;
            a1u = (kg >= 2) ? (bf16x8){0, 0, 0, 0, 0, 0, 0, 0} : a1r;
        }

        // ---- issue next group's A loads (hidden behind MFMA + scan) ----
        if (g + 1 < ngroups) {
            const int tg_n = dir ? (511 - ((g + 1) * 8 + tl)) : ((g + 1) * 8 + tl);
            if constexpr (L0) {
                const float* xr = (const float*)in_ +
                                  ((size_t)b_a * TT + tg_n) * 32 + kg * 8;
                xraw0 = *(const float4*)xr;
                xraw1 = *(const float4*)(xr + 4);
            } else {
                size_t rowoff = ((size_t)b_a * TT + tg_n) * 24;
                const unsigned short* p0 =
                    (kg < 3) ? (r0 + rowoff + 8 * kg) : (r1 + rowoff);
                const unsigned short* p1 =
                    (kg == 0) ? (r1 + rowoff + 8) : (r1 + rowoff + 16);
                a0r = *(const bf16x8*)p0;
                a1r = *(const bf16x8*)p1;
            }
        }

        // ---- MFMA (B-frags re-read from LDS each group) ----
        #pragma unroll
        for (int t = 0; t < 5; ++t) {
            bf16x8 b0 = *(const bf16x8*)&wih_lds[(t * 16 + m) * 72 + kg * 8];
            if constexpr (L0) {
                acc[t] = __builtin_amdgcn_mfma_f32_16x16x32_bf16(afr, b0,
                                                                 acc[t], 0, 0, 0);
            } else {
                bf16x8 b1 = *(const bf16x8*)&wih_lds[(t * 16 + m) * 72 + 32 + kg * 8];
                acc[t] = __builtin_amdgcn_mfma_f32_16x16x32_bf16(a0u, b0,
                                                                 acc[t], 0, 0, 0);
                acc[t] = __builtin_amdgcn_mfma_f32_16x16x32_bf16(a1u, b1,
                                                                 acc[t], 0, 0, 0);
            }
        }

        // ---- D -> per-wave LDS tile [m2][84] ----
        // In-order DS pipe: prev group's xg reads complete before these
        // writes; wbar stops compiler reordering.
        wbar();
        #pragma unroll
        for (int t = 0; t < 5; ++t) {
            #pragma unroll
            for (int reg = 0; reg < 4; ++reg) {
                int m2 = kg * 4 + reg;   // D row = (lane>>4)*4+reg
                int n  = t * 16 + m;     // D col = lane&15
                xw[m2 * 84 + n] = acc[t][reg];
            }
        }
        wbar();

        // ---- prefetch this group's xg (3 rows x 8 steps) into registers ----
        float xgr[8][3];
        #pragma unroll
        for (int s = 0; s < 8; ++s) {
            const float* xr2 = &xw[(bl * 8 + s) * 84];
            xgr[s][0] = xr2[u];
            xgr[s][1] = xr2[23 + u];
            xgr[s][2] = xr2[46 + u];
        }

        // ---- 8 scan steps; h via LDS f32, matvec via v_pk_fma_f32 ----
        #pragma unroll
        for (int s8 = 0; s8 < 8; ++s8) {
            const f32x2* hp = (const f32x2*)&hw[(s8 * 2 + bl) * 24];  // prev h
            f32x2 c0 = {bh[0], 0.f}, c1 = {bh[1], 0.f}, c2 = {bh[2], 0.f};
            #pragma unroll
            for (int k = 0; k < 12; ++k) {
                f32x2 hv = hp[k];
                c0 = __builtin_elementwise_fma(wrp[0][k], hv, c0);
                c1 = __builtin_elementwise_fma(wrp[1][k], hv, c1);
                c2 = __builtin_elementwise_fma(wrp[2][k], hv, c2);
            }
            float a0 = c0.x + c0.y, a1 = c1.x + c1.y, a2 = c2.x + c2.y;
            float r_ = sigm(xgr[s8][0] + a0);
            float z_ = sigm(xgr[s8][1] + a1);
            float n_ = tanh_(__builtin_fmaf(r_, a2, xgr[s8][2]));
            float hnew = n_ + z_ * (hold - n_);
            hold = hnew;
            if (lastOnly && u < 23) {
                int tg = dir ? (511 - (g * 8 + s8)) : (g * 8 + s8);
                if (tg == TT - 1) lastbuf[bg * 48 + dir * 23 + u] = hnew;
            }
            wbar();
            if (u < 24) hw[((s8 + 1) * 2 + bl) * 24 + u] = hnew;
            wbar();   // next step's reads stay after this write (in-order DS)
        }

        // ---- cooperative coalesced store of the 8-step block ----
        if (!lastOnly) {
            #pragma unroll
            for (int c = 0; c < 3; ++c) {
                f32x2 hv = *(const f32x2*)&hw[ldsoff[c]];
                float lo = hv.x;
                float hi = (cparr[c] == 11) ? 0.f : hv.y;     // col 23 := 0
                unsigned pack = (unsigned)f2bf(lo) | ((unsigned)f2bf(hi) << 16);
                int tg = dir ? (511 - (g * 8 + sarr[c])) : (g * 8 + sarr[c]);
                *(unsigned*)(dstbase + (size_t)tg * 24 + 2 * cparr[c]) = pack;
            }
        }
        // carry h into row 0 for next group (disjoint from store-phase rows)
        if (u < 24) hw[bl * 24 + u] = hold;
        wbar();
    }
}

__global__ __launch_bounds__(256) void fc_kernel(
    const float* __restrict__ last, const float* __restrict__ fcw,
    const float* __restrict__ fcb, const float* __restrict__ ostd,
    const float* __restrict__ omean, float* __restrict__ out)
{
    int idx = blockIdx.x * 256 + threadIdx.x;
    if (idx >= BB * NOUT) return;
    int b = idx >> 3, o = idx & 7;
    float acc = fcb[o];
    const float* lr = last + b * 48;
    const float* wr = fcw + o * 46;
    #pragma unroll
    for (int i = 0; i < 46; i++) acc += lr[i] * wr[i];
    out[idx] = acc * ostd[o] + omean[o];
}

extern "C" void kernel_launch(void* const* d_in, const int* in_sizes, int n_in,
                              void* d_out, int out_size, void* d_ws,
                              size_t ws_size, hipStream_t stream)
{
    const float* x     = (const float*)d_in[0];
    const float* fmean = (const float*)d_in[1];
    const float* fstd  = (const float*)d_in[2];
    const float* omean = (const float*)d_in[3];
    const float* ostd  = (const float*)d_in[4];
    const float* wih0  = (const float*)d_in[5];
    const float* whh0  = (const float*)d_in[6];
    const float* bih0  = (const float*)d_in[7];
    const float* bhh0  = (const float*)d_in[8];
    const float* wihr  = (const float*)d_in[9];
    const float* whhr  = (const float*)d_in[10];
    const float* bihr  = (const float*)d_in[11];
    const float* bhhr  = (const float*)d_in[12];
    const float* fcw   = (const float*)d_in[13];
    const float* fcb   = (const float*)d_in[14];

    char* ws = (char*)d_ws;
    const size_t bufBytes = 2 * DSTRIDE * sizeof(__hip_bfloat16);  // 96 MiB
    __hip_bfloat16* buf0 = (__hip_bfloat16*)ws;
    __hip_bfloat16* buf1 = (__hip_bfloat16*)(ws + bufBytes);
    float* lastb         = (float*)(ws + 2 * bufBytes);

    dim3 grid(BB / 8, 2);

    gru_mfma<true><<<grid, 256, 0, stream>>>(x, fmean, fstd, wih0, whh0, bih0,
                                             bhh0, buf0, nullptr, 0);
    gru_mfma<false><<<grid, 256, 0, stream>>>(
        buf0, nullptr, nullptr, wihr + 0 * 2 * 69 * 46, whhr + 0 * 2 * 69 * 23,
        bihr + 0 * 2 * 69, bhhr + 0 * 2 * 69, buf1, nullptr, 0);
    gru_mfma<false><<<grid, 256, 0, stream>>>(
        buf1, nullptr, nullptr, wihr + 1 * 2 * 69 * 46, whhr + 1 * 2 * 69 * 23,
        bihr + 1 * 2 * 69, bhhr + 1 * 2 * 69, nullptr, lastb, 1);
    fc_kernel<<<(BB * NOUT + 255) / 256, 256, 0, stream>>>(lastb, fcw, fcb, ostd,
                                                           omean, (float*)d_out);
}

// Round 9
// 677.856 us; speedup vs baseline: 1.3123x; 1.3123x over previous
//
#include <hip/hip_runtime.h>
#include <hip/hip_bf16.h>

constexpr int TT = 512, BB = 2048, NOUT = 8;
constexpr size_t DSTRIDE = (size_t)BB * TT * 24;   // bf16 elems per dir region

typedef __attribute__((ext_vector_type(8))) short bf16x8;
typedef __attribute__((ext_vector_type(4))) float f32x4;
typedef __attribute__((ext_vector_type(2))) float f32x2;

// fast device math: v_exp_f32 / v_rcp_f32 (1-ulp approx, no div sequence)
__device__ __forceinline__ float sigm(float x) {
    float e = __builtin_amdgcn_exp2f(x * -1.4426950408889634f);
    return __builtin_amdgcn_rcpf(1.f + e);
}
__device__ __forceinline__ float tanh_(float x) {
    float e = __builtin_amdgcn_exp2f(x * 2.8853900817779268f);
    return __builtin_fmaf(-2.f, __builtin_amdgcn_rcpf(e + 1.f), 1.f);
}
__device__ __forceinline__ unsigned short f2bf(float x) {
    __hip_bfloat16 h = __float2bfloat16(x);
    unsigned short s;
    __builtin_memcpy(&s, &h, 2);
    return s;
}
__device__ __forceinline__ void wbar() { __builtin_amdgcn_wave_barrier(); }

// Wave-autonomous BiGRU layer; input gates via MFMA (b_ih + r/z b_hh folded
// into acc init), hidden matvec via v_pk_fma_f32 from register W_hh, h
// broadcast as f32 through per-wave LDS (6x ds_read_b128/step, broadcast).
// W_ih B-frags in LDS laid out [tile][kslot][lane]x16B -> 2-way banks (free).
// Steady state: no lgkmcnt fences (one wave's DS ops execute in order; data
// waits compiler-inserted). A-frags software-pipelined one group ahead.
// block = 256 = 4 waves; wave owns 2 batch elems. grid = (BB/8, 2 dirs).
template <bool L0>
__global__ __launch_bounds__(256) void gru_mfma(
    const void* __restrict__ in_,        // L0: x [B][T][32] f32; else region0 (region1 at +DSTRIDE)
    const float* __restrict__ fmean, const float* __restrict__ fstd,
    const float* __restrict__ wih_g, const float* __restrict__ whh_g,
    const float* __restrict__ bih_g, const float* __restrict__ bhh_g,
    __hip_bfloat16* __restrict__ outbuf, float* __restrict__ lastbuf,
    int lastOnly)
{
    constexpr int KIN = L0 ? 32 : 46;

    // [tile t<5][kslot<8][lane m<16][8 shorts]: frag for (row t*16+m, k kslot*8..+7)
    __shared__ __align__(16) short  wih_lds[5 * 8 * 16 * 8];
    __shared__ __align__(16) float  whh_s[80 * 24];       // W_hh f32
    __shared__ __align__(16) float  xg_s[4][16 * 84];     // per-wave D tile
    __shared__ __align__(16) float  hist_s[4 * 9 * 2 * 24];  // h history f32
    __shared__ float bih_s[80], bhh_s[80];
    __shared__ __align__(16) float an_s[32], cn_s[32];

    const int tid = threadIdx.x, wv = tid >> 6, lane = tid & 63;
    const int bl = lane >> 5, u = lane & 31;
    const int m  = lane & 15, kg = lane >> 4;             // MFMA lane coords
    const int dir = blockIdx.y;
    const int bg  = blockIdx.x * 8 + wv * 2 + bl;

    const float* wih_d = wih_g + dir * 69 * KIN;
    const float* whh_d = whh_g + dir * 69 * 23;

    // ---- stage W_ih frags [t][kslot][m][8], col-remapped, zero-padded ----
    for (int idx = tid; idx < 5120; idx += 256) {
        int t = idx >> 10, r = idx & 1023;
        int kslot = r >> 7, mm = (r >> 3) & 15, j = r & 7;
        int row = t * 16 + mm, k = kslot * 8 + j;
        float v = 0.f;
        if (row < 69) {
            if constexpr (L0) {
                if (k < 32) v = wih_d[row * 32 + k];
            } else {
                if (k < 23) v = wih_d[row * 46 + k];                      // fwd
                else if (k >= 24 && k < 47) v = wih_d[row * 46 + k - 1];  // bwd
            }
        }
        wih_lds[idx] = (short)f2bf(v);
    }
    for (int idx = tid; idx < 80 * 24; idx += 256) {
        int j = idx / 24, k = idx - j * 24;
        whh_s[idx] = (j < 69 && k < 23) ? whh_d[j * 23 + k] : 0.f;
    }
    for (int idx = tid; idx < 80; idx += 256) {
        bih_s[idx] = (idx < 69) ? bih_g[dir * 69 + idx] : 0.f;
        bhh_s[idx] = (idx < 69) ? bhh_g[dir * 69 + idx] : 0.f;
    }
    for (int idx = tid; idx < 4 * 9 * 2 * 24; idx += 256) hist_s[idx] = 0.f;
    if (L0 && tid < 32) {
        float sd = fstd[tid];
        float sa = (sd == 0.f) ? 1.f : sd;        // std==0 -> 1
        float a  = (sa == 1.f) ? 0.f : 1.f / sa;  // adjusted std==1 -> zero
        an_s[tid] = a;
        cn_s[tid] = -fmean[tid] * a;
    }
    __syncthreads();   // only block-wide barrier

    // ---- per-lane W_hh rows (u, 23+u, 46+u) as f32 pairs -> 72 VGPRs ----
    f32x2 wrp[3][12];
    float bh2;
    #pragma unroll
    for (int r = 0; r < 3; ++r) {
        int row = r * 23 + u;   // <= 77 < 80
        #pragma unroll
        for (int k = 0; k < 12; ++k)
            wrp[r][k] = *(const f32x2*)&whh_s[row * 24 + 2 * k];
    }
    bh2 = bhh_s[46 + u];   // n-row b_hh stays inside r*(...)
    // D-tile bias: b_ih (+ b_hh for r/z rows, which add outside the r gate)
    float bi5[5];
    #pragma unroll
    for (int t = 0; t < 5; ++t) {
        int n = t * 16 + m;
        bi5[t] = bih_s[n] + (n < 46 ? bhh_s[n] : 0.f);
    }

    float an8[L0 ? 8 : 1], cn8[L0 ? 8 : 1];
    if constexpr (L0) {
        #pragma unroll
        for (int j = 0; j < 8; ++j) {
            an8[j] = an_s[kg * 8 + j];
            cn8[j] = cn_s[kg * 8 + j];
        }
    }

    float* xw = &xg_s[wv][0];
    float* hw = &hist_s[wv * 9 * 2 * 24];
    const int ngroups = (lastOnly && dir == 1) ? 1 : 64;
    float hold = 0.f;

    // ---- store-phase lane constants (hoisted) ----
    int sarr[3], cparr[3], ldsoff[3];
    {
        int idx = lane & 31;
        #pragma unroll
        for (int c = 0; c < 3; ++c) {
            int p = idx + 32 * c;             // 0..95
            sarr[c]  = p / 12;
            cparr[c] = p - 12 * sarr[c];
            ldsoff[c] = ((sarr[c] + 1) * 2 + bl) * 24 + 2 * cparr[c];
        }
    }
    unsigned short* dstbase = nullptr;
    if (!lastOnly)
        dstbase = (unsigned short*)outbuf + dir * DSTRIDE + (size_t)bg * TT * 24;

    // A-row coords: m = bl_a*8 + tl
    const int bl_a = m >> 3, tl = m & 7;
    const int b_a  = blockIdx.x * 8 + wv * 2 + bl_a;

    const unsigned short* r0 = (const unsigned short*)in_;
    const unsigned short* r1 = r0 + DSTRIDE;
    const bf16x8* bfrag = (const bf16x8*)wih_lds;   // [t*8+kslot][m]

    // ---- prefetch A-fragment raw data for group 0 ----
    float4 xraw0, xraw1;                 // L0 raw x
    bf16x8 a0r, a1r;                     // !L0 bf16 frags
    {
        const int tg_a = dir ? (511 - tl) : tl;
        if constexpr (L0) {
            const float* xr = (const float*)in_ +
                              ((size_t)b_a * TT + tg_a) * 32 + kg * 8;
            xraw0 = *(const float4*)xr;
            xraw1 = *(const float4*)(xr + 4);
        } else {
            size_t rowoff = ((size_t)b_a * TT + tg_a) * 24;
            const unsigned short* p0 =
                (kg < 3) ? (r0 + rowoff + 8 * kg) : (r1 + rowoff);
            const unsigned short* p1 =
                (kg == 0) ? (r1 + rowoff + 8) : (r1 + rowoff + 16);
            a0r = *(const bf16x8*)p0;
            a1r = *(const bf16x8*)p1;
        }
    }

    for (int g = 0; g < ngroups; ++g) {
        // ---- build A-frags from prefetched raw; acc init = bias ----
        f32x4 acc[5];
        #pragma unroll
        for (int t = 0; t < 5; ++t)
            acc[t] = (f32x4){bi5[t], bi5[t], bi5[t], bi5[t]};

        bf16x8 afr, a0u, a1u;
        if constexpr (L0) {
            float xv[8] = {xraw0.x, xraw0.y, xraw0.z, xraw0.w,
                           xraw1.x, xraw1.y, xraw1.z, xraw1.w};
            #pragma unroll
            for (int j = 0; j < 8; ++j)
                afr[j] = (short)f2bf(xv[j] * an8[j] + cn8[j]);
        } else {
            a0u = a0r;
            a1u = (kg >= 2) ? (bf16x8){0, 0, 0, 0, 0, 0, 0, 0} : a1r;
        }

        // ---- issue next group's A loads (hidden behind MFMA + scan) ----
        if (g + 1 < ngroups) {
            const int tg_n = dir ? (511 - ((g + 1) * 8 + tl)) : ((g + 1) * 8 + tl);
            if constexpr (L0) {
                const float* xr = (const float*)in_ +
                                  ((size_t)b_a * TT + tg_n) * 32 + kg * 8;
                xraw0 = *(const float4*)xr;
                xraw1 = *(const float4*)(xr + 4);
            } else {
                size_t rowoff = ((size_t)b_a * TT + tg_n) * 24;
                const unsigned short* p0 =
                    (kg < 3) ? (r0 + rowoff + 8 * kg) : (r1 + rowoff);
                const unsigned short* p1 =
                    (kg == 0) ? (r1 + rowoff + 8) : (r1 + rowoff + 16);
                a0r = *(const bf16x8*)p0;
                a1r = *(const bf16x8*)p1;
            }
        }

        // ---- MFMA (B-frags from swizzled LDS: 2-way banks, free) ----
        #pragma unroll
        for (int t = 0; t < 5; ++t) {
            bf16x8 b0 = bfrag[(t * 8 + kg) * 16 + m];
            if constexpr (L0) {
                acc[t] = __builtin_amdgcn_mfma_f32_16x16x32_bf16(afr, b0,
                                                                 acc[t], 0, 0, 0);
            } else {
                bf16x8 b1 = bfrag[(t * 8 + 4 + kg) * 16 + m];
                acc[t] = __builtin_amdgcn_mfma_f32_16x16x32_bf16(a0u, b0,
                                                                 acc[t], 0, 0, 0);
                acc[t] = __builtin_amdgcn_mfma_f32_16x16x32_bf16(a1u, b1,
                                                                 acc[t], 0, 0, 0);
            }
        }

        // ---- D -> per-wave LDS tile [m2][84] ----
        wbar();   // prev group's xg reads precede (in-order DS)
        #pragma unroll
        for (int t = 0; t < 5; ++t) {
            #pragma unroll
            for (int reg = 0; reg < 4; ++reg) {
                int m2 = kg * 4 + reg;   // D row = (lane>>4)*4+reg
                int n  = t * 16 + m;     // D col = lane&15
                xw[m2 * 84 + n] = acc[t][reg];
            }
        }
        wbar();

        // ---- prefetch this group's xg (3 rows x 8 steps) into registers ----
        float xgr[8][3];
        #pragma unroll
        for (int s = 0; s < 8; ++s) {
            const float* xr2 = &xw[(bl * 8 + s) * 84];
            xgr[s][0] = xr2[u];
            xgr[s][1] = xr2[23 + u];
            xgr[s][2] = xr2[46 + u];
        }

        // ---- 8 scan steps; h via LDS f32 (6x b128), v_pk_fma_f32 matvec ----
        #pragma unroll
        for (int s8 = 0; s8 < 8; ++s8) {
            const f32x4* hp4 = (const f32x4*)&hw[(s8 * 2 + bl) * 24];
            f32x4 hq[6];
            #pragma unroll
            for (int q = 0; q < 6; ++q) hq[q] = hp4[q];
            f32x2 c0 = {xgr[s8][0], 0.f};   // r/z bias pre-folded in D tile
            f32x2 c1 = {xgr[s8][1], 0.f};
            f32x2 c2 = {bh2, 0.f};
            #pragma unroll
            for (int k = 0; k < 12; ++k) {
                f32x2 hv = {hq[k >> 1][(k & 1) * 2], hq[k >> 1][(k & 1) * 2 + 1]};
                c0 = __builtin_elementwise_fma(wrp[0][k], hv, c0);
                c1 = __builtin_elementwise_fma(wrp[1][k], hv, c1);
                c2 = __builtin_elementwise_fma(wrp[2][k], hv, c2);
            }
            float r_ = sigm(c0.x + c0.y);
            float z_ = sigm(c1.x + c1.y);
            float n_ = tanh_(__builtin_fmaf(r_, c2.x + c2.y, xgr[s8][2]));
            float hnew = n_ + z_ * (hold - n_);
            hold = hnew;
            if (lastOnly && u < 23) {
                int tg = dir ? (511 - (g * 8 + s8)) : (g * 8 + s8);
                if (tg == TT - 1) lastbuf[bg * 48 + dir * 23 + u] = hnew;
            }
            wbar();
            if (u < 24) hw[((s8 + 1) * 2 + bl) * 24 + u] = hnew;
            wbar();   // next step's reads stay after this write (in-order DS)
        }

        // ---- cooperative coalesced store of the 8-step block ----
        if (!lastOnly) {
            #pragma unroll
            for (int c = 0; c < 3; ++c) {
                f32x2 hv = *(const f32x2*)&hw[ldsoff[c]];
                float lo = hv.x;
                float hi = (cparr[c] == 11) ? 0.f : hv.y;     // col 23 := 0
                unsigned pack = (unsigned)f2bf(lo) | ((unsigned)f2bf(hi) << 16);
                int tg = dir ? (511 - (g * 8 + sarr[c])) : (g * 8 + sarr[c]);
                *(unsigned*)(dstbase + (size_t)tg * 24 + 2 * cparr[c]) = pack;
            }
        }
        // carry h into row 0 for next group (disjoint from store-phase rows)
        if (u < 24) hw[bl * 24 + u] = hold;
        wbar();
    }
}

__global__ __launch_bounds__(256) void fc_kernel(
    const float* __restrict__ last, const float* __restrict__ fcw,
    const float* __restrict__ fcb, const float* __restrict__ ostd,
    const float* __restrict__ omean, float* __restrict__ out)
{
    int idx = blockIdx.x * 256 + threadIdx.x;
    if (idx >= BB * NOUT) return;
    int b = idx >> 3, o = idx & 7;
    float acc = fcb[o];
    const float* lr = last + b * 48;
    const float* wr = fcw + o * 46;
    #pragma unroll
    for (int i = 0; i < 46; i++) acc += lr[i] * wr[i];
    out[idx] = acc * ostd[o] + omean[o];
}

extern "C" void kernel_launch(void* const* d_in, const int* in_sizes, int n_in,
                              void* d_out, int out_size, void* d_ws,
                              size_t ws_size, hipStream_t stream)
{
    const float* x     = (const float*)d_in[0];
    const float* fmean = (const float*)d_in[1];
    const float* fstd  = (const float*)d_in[2];
    const float* omean = (const float*)d_in[3];
    const float* ostd  = (const float*)d_in[4];
    const float* wih0  = (const float*)d_in[5];
    const float* whh0  = (const float*)d_in[6];
    const float* bih0  = (const float*)d_in[7];
    const float* bhh0  = (const float*)d_in[8];
    const float* wihr  = (const float*)d_in[9];
    const float* whhr  = (const float*)d_in[10];
    const float* bihr  = (const float*)d_in[11];
    const float* bhhr  = (const float*)d_in[12];
    const float* fcw   = (const float*)d_in[13];
    const float* fcb   = (const float*)d_in[14];

    char* ws = (char*)d_ws;
    const size_t bufBytes = 2 * DSTRIDE * sizeof(__hip_bfloat16);  // 96 MiB
    __hip_bfloat16* buf0 = (__hip_bfloat16*)ws;
    __hip_bfloat16* buf1 = (__hip_bfloat16*)(ws + bufBytes);
    float* lastb         = (float*)(ws + 2 * bufBytes);

    dim3 grid(BB / 8, 2);

    gru_mfma<true><<<grid, 256, 0, stream>>>(x, fmean, fstd, wih0, whh0, bih0,
                                             bhh0, buf0, nullptr, 0);
    gru_mfma<false><<<grid, 256, 0, stream>>>(
        buf0, nullptr, nullptr, wihr + 0 * 2 * 69 * 46, whhr + 0 * 2 * 69 * 23,
        bihr + 0 * 2 * 69, bhhr + 0 * 2 * 69, buf1, nullptr, 0);
    gru_mfma<false><<<grid, 256, 0, stream>>>(
        buf1, nullptr, nullptr, wihr + 1 * 2 * 69 * 46, whhr + 1 * 2 * 69 * 23,
        bihr + 1 * 2 * 69, bhhr + 1 * 2 * 69, nullptr, lastb, 1);
    fc_kernel<<<(BB * NOUT + 255) / 256, 256, 0, stream>>>(lastb, fcw, fcb, ostd,
                                                           omean, (float*)d_out);
}

// Round 10
// 648.384 us; speedup vs baseline: 1.3720x; 1.0455x over previous
//
#include <hip/hip_runtime.h>
#include <hip/hip_bf16.h>

constexpr int TT = 512, BB = 2048, NOUT = 8;
constexpr size_t DSTRIDE = (size_t)BB * TT * 24;   // bf16 elems per dir region

typedef __attribute__((ext_vector_type(8))) short bf16x8;
typedef __attribute__((ext_vector_type(4))) float f32x4;
typedef __attribute__((ext_vector_type(2))) float f32x2;
typedef __attribute__((ext_vector_type(2))) _Float16 f16x2;

// fast device math: v_exp_f32 / v_rcp_f32 (1-ulp approx, no div sequence)
__device__ __forceinline__ float sigm(float x) {
    float e = __builtin_amdgcn_exp2f(x * -1.4426950408889634f);
    return __builtin_amdgcn_rcpf(1.f + e);
}
__device__ __forceinline__ float tanh_(float x) {
    float e = __builtin_amdgcn_exp2f(x * 2.8853900817779268f);
    return __builtin_fmaf(-2.f, __builtin_amdgcn_rcpf(e + 1.f), 1.f);
}
__device__ __forceinline__ unsigned short f2bf(float x) {
    __hip_bfloat16 h = __float2bfloat16(x);
    unsigned short s;
    __builtin_memcpy(&s, &h, 2);
    return s;
}
__device__ __forceinline__ f16x2 asf16x2(unsigned v) {
    f16x2 r; __builtin_memcpy(&r, &v, 4); return r;
}
__device__ __forceinline__ void wbar() { __builtin_amdgcn_wave_barrier(); }

// Wave-autonomous BiGRU layer. LDS-pipe diet (R8 was LDS-bound at ~8.2k
// cyc/CU/group): h history in f16 (3x ds_read_b128/step), hidden matvec via
// v_dot2_f32_f16 (W_hh f16 pairs, 36 VGPRs), W_ih B-frags register-resident
// (no per-group LDS reads). Input gates via MFMA (b_ih + r/z b_hh folded into
// acc init). Steady state: no lgkmcnt fences (one wave's DS ops execute in
// order; data waits compiler-inserted). A-frags software-pipelined one group
// ahead. block = 256 = 4 waves; wave owns 2 batch elems. grid = (BB/8, 2).
template <bool L0>
__global__ __launch_bounds__(256) void gru_mfma(
    const void* __restrict__ in_,        // L0: x [B][T][32] f32; else region0 (region1 at +DSTRIDE)
    const float* __restrict__ fmean, const float* __restrict__ fstd,
    const float* __restrict__ wih_g, const float* __restrict__ whh_g,
    const float* __restrict__ bih_g, const float* __restrict__ bhh_g,
    __hip_bfloat16* __restrict__ outbuf, float* __restrict__ lastbuf,
    int lastOnly)
{
    constexpr int KIN = L0 ? 32 : 46;
    constexpr int KF  = L0 ? 1 : 2;

    // [tile t<5][kslot<8][lane m<16][8 shorts] staging for B-frags
    __shared__ __align__(16) short     wih_lds[5 * 8 * 16 * 8];
    __shared__ __align__(16) _Float16  whh_h[80 * 24];       // W_hh f16
    __shared__ __align__(16) float     xg_s[4][16 * 84];     // per-wave D tile
    __shared__ __align__(16) _Float16  hist_h[4 * 9 * 2 * 24];  // h history f16
    __shared__ float bih_s[80], bhh_s[80];
    __shared__ __align__(16) float an_s[32], cn_s[32];

    const int tid = threadIdx.x, wv = tid >> 6, lane = tid & 63;
    const int bl = lane >> 5, u = lane & 31;
    const int m  = lane & 15, kg = lane >> 4;             // MFMA lane coords
    const int dir = blockIdx.y;
    const int bg  = blockIdx.x * 8 + wv * 2 + bl;

    const float* wih_d = wih_g + dir * 69 * KIN;
    const float* whh_d = whh_g + dir * 69 * 23;

    // ---- stage W_ih frags [t][kslot][m][8], col-remapped, zero-padded ----
    for (int idx = tid; idx < 5120; idx += 256) {
        int t = idx >> 10, r = idx & 1023;
        int kslot = r >> 7, mm = (r >> 3) & 15, j = r & 7;
        int row = t * 16 + mm, k = kslot * 8 + j;
        float v = 0.f;
        if (row < 69) {
            if constexpr (L0) {
                if (k < 32) v = wih_d[row * 32 + k];
            } else {
                if (k < 23) v = wih_d[row * 46 + k];                      // fwd
                else if (k >= 24 && k < 47) v = wih_d[row * 46 + k - 1];  // bwd
            }
        }
        wih_lds[idx] = (short)f2bf(v);
    }
    for (int idx = tid; idx < 80 * 24; idx += 256) {
        int j = idx / 24, k = idx - j * 24;
        whh_h[idx] = (j < 69 && k < 23) ? (_Float16)whh_d[j * 23 + k]
                                        : (_Float16)0.f;
    }
    for (int idx = tid; idx < 80; idx += 256) {
        bih_s[idx] = (idx < 69) ? bih_g[dir * 69 + idx] : 0.f;
        bhh_s[idx] = (idx < 69) ? bhh_g[dir * 69 + idx] : 0.f;
    }
    for (int idx = tid; idx < 4 * 9 * 2 * 24; idx += 256)
        hist_h[idx] = (_Float16)0.f;
    if (L0 && tid < 32) {
        float sd = fstd[tid];
        float sa = (sd == 0.f) ? 1.f : sd;        // std==0 -> 1
        float a  = (sa == 1.f) ? 0.f : 1.f / sa;  // adjusted std==1 -> zero
        an_s[tid] = a;
        cn_s[tid] = -fmean[tid] * a;
    }
    __syncthreads();   // only block-wide barrier

    // ---- per-lane W_hh rows (u, 23+u, 46+u) as f16 pairs -> 36 VGPRs ----
    unsigned wrp[3][12];
    float bh2;
    #pragma unroll
    for (int r = 0; r < 3; ++r) {
        int row = r * 23 + u;   // <= 77 < 80
        #pragma unroll
        for (int k = 0; k < 12; ++k)
            wrp[r][k] = *(const unsigned*)&whh_h[row * 24 + 2 * k];
    }
    bh2 = bhh_s[46 + u];   // n-row b_hh stays inside r*(...)
    // D-tile bias: b_ih (+ b_hh for r/z rows, which add outside the r gate)
    float bi5[5];
    #pragma unroll
    for (int t = 0; t < 5; ++t) {
        int n = t * 16 + m;
        bi5[t] = bih_s[n] + (n < 46 ? bhh_s[n] : 0.f);
    }

    // ---- B-fragments register-resident (no per-group LDS reads) ----
    const bf16x8* bfrag = (const bf16x8*)wih_lds;   // [t*8+kslot][m]
    bf16x8 bfr[5][KF];
    #pragma unroll
    for (int t = 0; t < 5; ++t)
        #pragma unroll
        for (int kf = 0; kf < KF; ++kf)
            bfr[t][kf] = bfrag[(t * 8 + kf * 4 + kg) * 16 + m];

    float an8[L0 ? 8 : 1], cn8[L0 ? 8 : 1];
    if constexpr (L0) {
        #pragma unroll
        for (int j = 0; j < 8; ++j) {
            an8[j] = an_s[kg * 8 + j];
            cn8[j] = cn_s[kg * 8 + j];
        }
    }

    float* xw = &xg_s[wv][0];
    _Float16* hw = &hist_h[wv * 9 * 2 * 24];
    const int ngroups = (lastOnly && dir == 1) ? 1 : 64;
    float hold = 0.f;

    // ---- store-phase lane constants (hoisted) ----
    int sarr[3], cparr[3], ldsoff[3];
    {
        int idx = lane & 31;
        #pragma unroll
        for (int c = 0; c < 3; ++c) {
            int p = idx + 32 * c;             // 0..95
            sarr[c]  = p / 12;
            cparr[c] = p - 12 * sarr[c];
            ldsoff[c] = ((sarr[c] + 1) * 2 + bl) * 24 + 2 * cparr[c];
        }
    }
    unsigned short* dstbase = nullptr;
    if (!lastOnly)
        dstbase = (unsigned short*)outbuf + dir * DSTRIDE + (size_t)bg * TT * 24;

    // A-row coords: m = bl_a*8 + tl
    const int bl_a = m >> 3, tl = m & 7;
    const int b_a  = blockIdx.x * 8 + wv * 2 + bl_a;

    const unsigned short* r0 = (const unsigned short*)in_;
    const unsigned short* r1 = r0 + DSTRIDE;

    // ---- prefetch A-fragment raw data for group 0 ----
    float4 xraw0, xraw1;                 // L0 raw x
    bf16x8 a0r, a1r;                     // !L0 bf16 frags
    {
        const int tg_a = dir ? (511 - tl) : tl;
        if constexpr (L0) {
            const float* xr = (const float*)in_ +
                              ((size_t)b_a * TT + tg_a) * 32 + kg * 8;
            xraw0 = *(const float4*)xr;
            xraw1 = *(const float4*)(xr + 4);
        } else {
            size_t rowoff = ((size_t)b_a * TT + tg_a) * 24;
            const unsigned short* p0 =
                (kg < 3) ? (r0 + rowoff + 8 * kg) : (r1 + rowoff);
            const unsigned short* p1 =
                (kg == 0) ? (r1 + rowoff + 8) : (r1 + rowoff + 16);
            a0r = *(const bf16x8*)p0;
            a1r = *(const bf16x8*)p1;
        }
    }

    for (int g = 0; g < ngroups; ++g) {
        // ---- build A-frags from prefetched raw; acc init = bias ----
        f32x4 acc[5];
        #pragma unroll
        for (int t = 0; t < 5; ++t)
            acc[t] = (f32x4){bi5[t], bi5[t], bi5[t], bi5[t]};

        bf16x8 afr, a0u, a1u;
        if constexpr (L0) {
            float xv[8] = {xraw0.x, xraw0.y, xraw0.z, xraw0.w,
                           xraw1.x, xraw1.y, xraw1.z, xraw1.w};
            #pragma unroll
            for (int j = 0; j < 8; ++j)
                afr[j] = (short)f2bf(xv[j] * an8[j] + cn8[j]);
        } else {
            a0u = a0r;
            a1u = (kg >= 2) ? (bf16x8){0, 0, 0, 0, 0, 0, 0, 0} : a1r;
        }

        // ---- issue next group's A loads (hidden behind MFMA + scan) ----
        if (g + 1 < ngroups) {
            const int tg_n = dir ? (511 - ((g + 1) * 8 + tl)) : ((g + 1) * 8 + tl);
            if constexpr (L0) {
                const float* xr = (const float*)in_ +
                                  ((size_t)b_a * TT + tg_n) * 32 + kg * 8;
                xraw0 = *(const float4*)xr;
                xraw1 = *(const float4*)(xr + 4);
            } else {
                size_t rowoff = ((size_t)b_a * TT + tg_n) * 24;
                const unsigned short* p0 =
                    (kg < 3) ? (r0 + rowoff + 8 * kg) : (r1 + rowoff);
                const unsigned short* p1 =
                    (kg == 0) ? (r1 + rowoff + 8) : (r1 + rowoff + 16);
                a0r = *(const bf16x8*)p0;
                a1r = *(const bf16x8*)p1;
            }
        }

        // ---- MFMA (B-frags from registers) ----
        #pragma unroll
        for (int t = 0; t < 5; ++t) {
            if constexpr (L0) {
                acc[t] = __builtin_amdgcn_mfma_f32_16x16x32_bf16(afr, bfr[t][0],
                                                                 acc[t], 0, 0, 0);
            } else {
                acc[t] = __builtin_amdgcn_mfma_f32_16x16x32_bf16(a0u, bfr[t][0],
                                                                 acc[t], 0, 0, 0);
                acc[t] = __builtin_amdgcn_mfma_f32_16x16x32_bf16(a1u, bfr[t][1],
                                                                 acc[t], 0, 0, 0);
            }
        }

        // ---- D -> per-wave LDS tile [m2][84] ----
        wbar();   // prev group's xg reads precede (in-order DS)
        #pragma unroll
        for (int t = 0; t < 5; ++t) {
            #pragma unroll
            for (int reg = 0; reg < 4; ++reg) {
                int m2 = kg * 4 + reg;   // D row = (lane>>4)*4+reg
                int n  = t * 16 + m;     // D col = lane&15
                xw[m2 * 84 + n] = acc[t][reg];
            }
        }
        wbar();

        // ---- prefetch this group's xg (3 rows x 8 steps) into registers ----
        float xgr[8][3];
        #pragma unroll
        for (int s = 0; s < 8; ++s) {
            const float* xr2 = &xw[(bl * 8 + s) * 84];
            xgr[s][0] = xr2[u];
            xgr[s][1] = xr2[23 + u];
            xgr[s][2] = xr2[46 + u];
        }

        // ---- 8 scan steps; h via LDS f16 (3x b128), fdot2 matvec ----
        #pragma unroll
        for (int s8 = 0; s8 < 8; ++s8) {
            const _Float16* hr = &hw[(s8 * 2 + bl) * 24];   // prev h (f16)
            uint4 hq0 = *(const uint4*)hr;          // f16 0..7
            uint4 hq1 = *(const uint4*)(hr + 8);    // f16 8..15
            uint4 hq2 = *(const uint4*)(hr + 16);   // f16 16..23
            unsigned hwd[12] = {hq0.x, hq0.y, hq0.z, hq0.w,
                                hq1.x, hq1.y, hq1.z, hq1.w,
                                hq2.x, hq2.y, hq2.z, hq2.w};
            // dual accumulators per gate: 6-deep chains
            float a0a = xgr[s8][0], a1a = xgr[s8][1], a2a = bh2;
            float a0b = 0.f, a1b = 0.f, a2b = 0.f;
            #pragma unroll
            for (int k = 0; k < 6; ++k) {
                f16x2 hv = asf16x2(hwd[k]);
                a0a = __builtin_amdgcn_fdot2(asf16x2(wrp[0][k]), hv, a0a, false);
                a1a = __builtin_amdgcn_fdot2(asf16x2(wrp[1][k]), hv, a1a, false);
                a2a = __builtin_amdgcn_fdot2(asf16x2(wrp[2][k]), hv, a2a, false);
            }
            #pragma unroll
            for (int k = 6; k < 12; ++k) {
                f16x2 hv = asf16x2(hwd[k]);
                a0b = __builtin_amdgcn_fdot2(asf16x2(wrp[0][k]), hv, a0b, false);
                a1b = __builtin_amdgcn_fdot2(asf16x2(wrp[1][k]), hv, a1b, false);
                a2b = __builtin_amdgcn_fdot2(asf16x2(wrp[2][k]), hv, a2b, false);
            }
            float r_ = sigm(a0a + a0b);
            float z_ = sigm(a1a + a1b);
            float n_ = tanh_(__builtin_fmaf(r_, a2a + a2b, xgr[s8][2]));
            float hnew = n_ + z_ * (hold - n_);
            hold = hnew;
            if (lastOnly && u < 23) {
                int tg = dir ? (511 - (g * 8 + s8)) : (g * 8 + s8);
                if (tg == TT - 1) lastbuf[bg * 48 + dir * 23 + u] = hnew;
            }
            wbar();
            if (u < 24) hw[((s8 + 1) * 2 + bl) * 24 + u] = (_Float16)hnew;
            wbar();   // next step's reads stay after this write (in-order DS)
        }

        // ---- cooperative coalesced store of the 8-step block ----
        if (!lastOnly) {
            #pragma unroll
            for (int c = 0; c < 3; ++c) {
                f16x2 pf = asf16x2(*(const unsigned*)&hw[ldsoff[c]]);
                float lo = (float)pf[0];
                float hi = (cparr[c] == 11) ? 0.f : (float)pf[1];  // col 23 := 0
                unsigned pack = (unsigned)f2bf(lo) | ((unsigned)f2bf(hi) << 16);
                int tg = dir ? (511 - (g * 8 + sarr[c])) : (g * 8 + sarr[c]);
                *(unsigned*)(dstbase + (size_t)tg * 24 + 2 * cparr[c]) = pack;
            }
        }
        // carry h into row 0 for next group (disjoint from store-phase rows)
        if (u < 24) hw[bl * 24 + u] = (_Float16)hold;
        wbar();
    }
}

__global__ __launch_bounds__(256) void fc_kernel(
    const float* __restrict__ last, const float* __restrict__ fcw,
    const float* __restrict__ fcb, const float* __restrict__ ostd,
    const float* __restrict__ omean, float* __restrict__ out)
{
    int idx = blockIdx.x * 256 + threadIdx.x;
    if (idx >= BB * NOUT) return;
    int b = idx >> 3, o = idx & 7;
    float acc = fcb[o];
    const float* lr = last + b * 48;
    const float* wr = fcw + o * 46;
    #pragma unroll
    for (int i = 0; i < 46; i++) acc += lr[i] * wr[i];
    out[idx] = acc * ostd[o] + omean[o];
}

extern "C" void kernel_launch(void* const* d_in, const int* in_sizes, int n_in,
                              void* d_out, int out_size, void* d_ws,
                              size_t ws_size, hipStream_t stream)
{
    const float* x     = (const float*)d_in[0];
    const float* fmean = (const float*)d_in[1];
    const float* fstd  = (const float*)d_in[2];
    const float* omean = (const float*)d_in[3];
    const float* ostd  = (const float*)d_in[4];
    const float* wih0  = (const float*)d_in[5];
    const float* whh0  = (const float*)d_in[6];
    const float* bih0  = (const float*)d_in[7];
    const float* bhh0  = (const float*)d_in[8];
    const float* wihr  = (const float*)d_in[9];
    const float* whhr  = (const float*)d_in[10];
    const float* bihr  = (const float*)d_in[11];
    const float* bhhr  = (const float*)d_in[12];
    const float* fcw   = (const float*)d_in[13];
    const float* fcb   = (const float*)d_in[14];

    char* ws = (char*)d_ws;
    const size_t bufBytes = 2 * DSTRIDE * sizeof(__hip_bfloat16);  // 96 MiB
    __hip_bfloat16* buf0 = (__hip_bfloat16*)ws;
    __hip_bfloat16* buf1 = (__hip_bfloat16*)(ws + bufBytes);
    float* lastb         = (float*)(ws + 2 * bufBytes);

    dim3 grid(BB / 8, 2);

    gru_mfma<true><<<grid, 256, 0, stream>>>(x, fmean, fstd, wih0, whh0, bih0,
                                             bhh0, buf0, nullptr, 0);
    gru_mfma<false><<<grid, 256, 0, stream>>>(
        buf0, nullptr, nullptr, wihr + 0 * 2 * 69 * 46, whhr + 0 * 2 * 69 * 23,
        bihr + 0 * 2 * 69, bhhr + 0 * 2 * 69, buf1, nullptr, 0);
    gru_mfma<false><<<grid, 256, 0, stream>>>(
        buf1, nullptr, nullptr, wihr + 1 * 2 * 69 * 46, whhr + 1 * 2 * 69 * 23,
        bihr + 1 * 2 * 69, bhhr + 1 * 2 * 69, nullptr, lastb, 1);
    fc_kernel<<<(BB * NOUT + 255) / 256, 256, 0, stream>>>(lastb, fcw, fcb, ostd,
                                                           omean, (float*)d_out);
}

// Round 11
// 636.847 us; speedup vs baseline: 1.3968x; 1.0181x over previous
//
#include <hip/hip_runtime.h>
#include <hip/hip_bf16.h>

constexpr int TT = 512, BB = 2048, NOUT = 8;
constexpr size_t DSTRIDE = (size_t)BB * TT * 24;   // bf16 elems per dir region

typedef __attribute__((ext_vector_type(8))) short bf16x8;
typedef __attribute__((ext_vector_type(4))) float f32x4;
typedef __attribute__((ext_vector_type(2))) _Float16 f16x2;

// fast device math: v_exp_f32 / v_rcp_f32 (1-ulp approx, no div sequence)
__device__ __forceinline__ float sigm(float x) {
    float e = __builtin_amdgcn_exp2f(x * -1.4426950408889634f);
    return __builtin_amdgcn_rcpf(1.f + e);
}
__device__ __forceinline__ float tanh_(float x) {
    float e = __builtin_amdgcn_exp2f(x * 2.8853900817779268f);
    return __builtin_fmaf(-2.f, __builtin_amdgcn_rcpf(e + 1.f), 1.f);
}
__device__ __forceinline__ unsigned short f2bf(float x) {
    __hip_bfloat16 h = __float2bfloat16(x);
    unsigned short s;
    __builtin_memcpy(&s, &h, 2);
    return s;
}
__device__ __forceinline__ f16x2 asf16x2(unsigned v) {
    f16x2 r; __builtin_memcpy(&r, &v, 4); return r;
}
__device__ __forceinline__ void wbar() { __builtin_amdgcn_wave_barrier(); }

// Wave-autonomous BiGRU layer. R10: software-pipelined groups — D tile is
// double-buffered, MFMA(g+1) + D-writes are emitted before scan(g) so the
// scheduler interleaves them into scan stalls; h-history rows padded to 32
// (unconditional lane writes, no exec mask); LAST templated out of hot loop.
// h f16 (3x ds_read_b128/step), matvec fdot2, W_ih B-frags in registers.
// Steady state: no lgkmcnt fences (per-wave DS ops execute in order).
// block = 256 = 4 waves; wave owns 2 batch elems. grid = (BB/8, 2 dirs).
template <bool L0, bool LAST>
__global__ __launch_bounds__(256) void gru_mfma(
    const void* __restrict__ in_,        // L0: x [B][T][32] f32; else region0 (region1 at +DSTRIDE)
    const float* __restrict__ fmean, const float* __restrict__ fstd,
    const float* __restrict__ wih_g, const float* __restrict__ whh_g,
    const float* __restrict__ bih_g, const float* __restrict__ bhh_g,
    __hip_bfloat16* __restrict__ outbuf, float* __restrict__ lastbuf)
{
    constexpr int KIN = L0 ? 32 : 46;
    constexpr int KF  = L0 ? 1 : 2;

    // [tile t<5][kslot<8][lane m<16][8 shorts] staging for B-frags
    __shared__ __align__(16) short     wih_lds[5 * 8 * 16 * 8];
    __shared__ __align__(16) _Float16  whh_h[80 * 24];       // W_hh f16
    __shared__ __align__(16) float     xg_s[4][2][16 * 84];  // per-wave D dbuf
    __shared__ __align__(16) _Float16  hist_h[4 * 9 * 2 * 32];  // h history f16
    __shared__ float bih_s[80], bhh_s[80];
    __shared__ __align__(16) float an_s[32], cn_s[32];

    const int tid = threadIdx.x, wv = tid >> 6, lane = tid & 63;
    const int bl = lane >> 5, u = lane & 31;
    const int m  = lane & 15, kg = lane >> 4;             // MFMA lane coords
    const int dir = blockIdx.y;
    const int bg  = blockIdx.x * 8 + wv * 2 + bl;

    const float* wih_d = wih_g + dir * 69 * KIN;
    const float* whh_d = whh_g + dir * 69 * 23;

    // ---- stage W_ih frags [t][kslot][m][8], col-remapped, zero-padded ----
    for (int idx = tid; idx < 5120; idx += 256) {
        int t = idx >> 10, r = idx & 1023;
        int kslot = r >> 7, mm = (r >> 3) & 15, j = r & 7;
        int row = t * 16 + mm, k = kslot * 8 + j;
        float v = 0.f;
        if (row < 69) {
            if constexpr (L0) {
                if (k < 32) v = wih_d[row * 32 + k];
            } else {
                if (k < 23) v = wih_d[row * 46 + k];                      // fwd
                else if (k >= 24 && k < 47) v = wih_d[row * 46 + k - 1];  // bwd
            }
        }
        wih_lds[idx] = (short)f2bf(v);
    }
    for (int idx = tid; idx < 80 * 24; idx += 256) {
        int j = idx / 24, k = idx - j * 24;
        whh_h[idx] = (j < 69 && k < 23) ? (_Float16)whh_d[j * 23 + k]
                                        : (_Float16)0.f;
    }
    for (int idx = tid; idx < 80; idx += 256) {
        bih_s[idx] = (idx < 69) ? bih_g[dir * 69 + idx] : 0.f;
        bhh_s[idx] = (idx < 69) ? bhh_g[dir * 69 + idx] : 0.f;
    }
    for (int idx = tid; idx < 4 * 9 * 2 * 32; idx += 256)
        hist_h[idx] = (_Float16)0.f;
    if (L0 && tid < 32) {
        float sd = fstd[tid];
        float sa = (sd == 0.f) ? 1.f : sd;        // std==0 -> 1
        float a  = (sa == 1.f) ? 0.f : 1.f / sa;  // adjusted std==1 -> zero
        an_s[tid] = a;
        cn_s[tid] = -fmean[tid] * a;
    }
    __syncthreads();   // only block-wide barrier

    // ---- per-lane W_hh rows (u, 23+u, 46+u) as f16 pairs -> 36 VGPRs ----
    unsigned wrp[3][12];
    float bh2;
    #pragma unroll
    for (int r = 0; r < 3; ++r) {
        int row = r * 23 + u;   // <= 77 < 80
        #pragma unroll
        for (int k = 0; k < 12; ++k)
            wrp[r][k] = *(const unsigned*)&whh_h[row * 24 + 2 * k];
    }
    bh2 = bhh_s[46 + u];   // n-row b_hh stays inside r*(...)
    // D-tile bias: b_ih (+ b_hh for r/z rows, which add outside the r gate)
    float bi5[5];
    #pragma unroll
    for (int t = 0; t < 5; ++t) {
        int n = t * 16 + m;
        bi5[t] = bih_s[n] + (n < 46 ? bhh_s[n] : 0.f);
    }

    // ---- B-fragments register-resident ----
    const bf16x8* bfrag = (const bf16x8*)wih_lds;   // [t*8+kslot][m]
    bf16x8 bfr[5][KF];
    #pragma unroll
    for (int t = 0; t < 5; ++t)
        #pragma unroll
        for (int kf = 0; kf < KF; ++kf)
            bfr[t][kf] = bfrag[(t * 8 + kf * 4 + kg) * 16 + m];

    float an8[L0 ? 8 : 1], cn8[L0 ? 8 : 1];
    if constexpr (L0) {
        #pragma unroll
        for (int j = 0; j < 8; ++j) {
            an8[j] = an_s[kg * 8 + j];
            cn8[j] = cn_s[kg * 8 + j];
        }
    }

    float* db0 = &xg_s[wv][0][0];
    float* db1 = &xg_s[wv][1][0];
    _Float16* hw = &hist_h[wv * 9 * 2 * 32];
    const int ngroups = (LAST && dir == 1) ? 1 : 64;
    float hold = 0.f;

    // ---- store-phase lane constants (hoisted) ----
    int sarr[3], cparr[3], ldsoff[3];
    {
        int idx = lane & 31;
        #pragma unroll
        for (int c = 0; c < 3; ++c) {
            int p = idx + 32 * c;             // 0..95
            sarr[c]  = p / 12;
            cparr[c] = p - 12 * sarr[c];
            ldsoff[c] = ((sarr[c] + 1) * 2 + bl) * 32 + 2 * cparr[c];
        }
    }
    unsigned short* dstbase = nullptr;
    if constexpr (!LAST)
        dstbase = (unsigned short*)outbuf + dir * DSTRIDE + (size_t)bg * TT * 24;

    // A-row coords: m = bl_a*8 + tl
    const int bl_a = m >> 3, tl = m & 7;
    const int b_a  = blockIdx.x * 8 + wv * 2 + bl_a;

    const unsigned short* r0 = (const unsigned short*)in_;
    const unsigned short* r1 = r0 + DSTRIDE;

    float4 xraw0, xraw1;                 // L0 raw x
    bf16x8 a0r, a1r;                     // !L0 bf16 frags

    // ---- load raw A data for group 0 ----
    {
        const int tg_a = dir ? (511 - tl) : tl;
        if constexpr (L0) {
            const float* xr = (const float*)in_ +
                              ((size_t)b_a * TT + tg_a) * 32 + kg * 8;
            xraw0 = *(const float4*)xr;
            xraw1 = *(const float4*)(xr + 4);
        } else {
            size_t rowoff = ((size_t)b_a * TT + tg_a) * 24;
            const unsigned short* p0 =
                (kg < 3) ? (r0 + rowoff + 8 * kg) : (r1 + rowoff);
            const unsigned short* p1 =
                (kg == 0) ? (r1 + rowoff + 8) : (r1 + rowoff + 16);
            a0r = *(const bf16x8*)p0;
            a1r = *(const bf16x8*)p1;
        }
    }

    // ---- prologue: MFMA for group 0 -> db0 ----
    {
        f32x4 acc[5];
        #pragma unroll
        for (int t = 0; t < 5; ++t)
            acc[t] = (f32x4){bi5[t], bi5[t], bi5[t], bi5[t]};
        if constexpr (L0) {
            float xv[8] = {xraw0.x, xraw0.y, xraw0.z, xraw0.w,
                           xraw1.x, xraw1.y, xraw1.z, xraw1.w};
            bf16x8 afr;
            #pragma unroll
            for (int j = 0; j < 8; ++j)
                afr[j] = (short)f2bf(xv[j] * an8[j] + cn8[j]);
            #pragma unroll
            for (int t = 0; t < 5; ++t)
                acc[t] = __builtin_amdgcn_mfma_f32_16x16x32_bf16(afr, bfr[t][0],
                                                                 acc[t], 0, 0, 0);
        } else {
            bf16x8 a0u = a0r;
            bf16x8 a1u = (kg >= 2) ? (bf16x8){0,0,0,0,0,0,0,0} : a1r;
            #pragma unroll
            for (int t = 0; t < 5; ++t) {
                acc[t] = __builtin_amdgcn_mfma_f32_16x16x32_bf16(a0u, bfr[t][0],
                                                                 acc[t], 0, 0, 0);
                acc[t] = __builtin_amdgcn_mfma_f32_16x16x32_bf16(a1u, bfr[t][1],
                                                                 acc[t], 0, 0, 0);
            }
        }
        #pragma unroll
        for (int t = 0; t < 5; ++t)
            #pragma unroll
            for (int reg = 0; reg < 4; ++reg)
                db0[(kg * 4 + reg) * 84 + t * 16 + m] = acc[t][reg];
    }
    // ---- load raw A data for group 1 ----
    if (1 < ngroups) {
        const int tg_a = dir ? (511 - (8 + tl)) : (8 + tl);
        if constexpr (L0) {
            const float* xr = (const float*)in_ +
                              ((size_t)b_a * TT + tg_a) * 32 + kg * 8;
            xraw0 = *(const float4*)xr;
            xraw1 = *(const float4*)(xr + 4);
        } else {
            size_t rowoff = ((size_t)b_a * TT + tg_a) * 24;
            const unsigned short* p0 =
                (kg < 3) ? (r0 + rowoff + 8 * kg) : (r1 + rowoff);
            const unsigned short* p1 =
                (kg == 0) ? (r1 + rowoff + 8) : (r1 + rowoff + 16);
            a0r = *(const bf16x8*)p0;
            a1r = *(const bf16x8*)p1;
        }
    }

    int cur = 0;
    for (int g = 0; g < ngroups; ++g) {
        float* Dc = cur ? db1 : db0;
        float* Dn = cur ? db0 : db1;
        wbar();   // D(cur) writes precede in program order (in-order DS)

        // ---- prefetch this group's xg (3 rows x 8 steps) into registers ----
        float xgr[8][3];
        #pragma unroll
        for (int s = 0; s < 8; ++s) {
            const float* xr2 = &Dc[(bl * 8 + s) * 84];
            xgr[s][0] = xr2[u];
            xgr[s][1] = xr2[23 + u];
            xgr[s][2] = xr2[46 + u];
        }

        // ---- MFMA for group g+1 -> Dn (independent work, overlaps scan) ----
        if (g + 1 < ngroups) {
            f32x4 acc[5];
            #pragma unroll
            for (int t = 0; t < 5; ++t)
                acc[t] = (f32x4){bi5[t], bi5[t], bi5[t], bi5[t]};
            if constexpr (L0) {
                float xv[8] = {xraw0.x, xraw0.y, xraw0.z, xraw0.w,
                               xraw1.x, xraw1.y, xraw1.z, xraw1.w};
                bf16x8 afr;
                #pragma unroll
                for (int j = 0; j < 8; ++j)
                    afr[j] = (short)f2bf(xv[j] * an8[j] + cn8[j]);
                #pragma unroll
                for (int t = 0; t < 5; ++t)
                    acc[t] = __builtin_amdgcn_mfma_f32_16x16x32_bf16(
                        afr, bfr[t][0], acc[t], 0, 0, 0);
            } else {
                bf16x8 a0u = a0r;
                bf16x8 a1u = (kg >= 2) ? (bf16x8){0,0,0,0,0,0,0,0} : a1r;
                #pragma unroll
                for (int t = 0; t < 5; ++t) {
                    acc[t] = __builtin_amdgcn_mfma_f32_16x16x32_bf16(
                        a0u, bfr[t][0], acc[t], 0, 0, 0);
                    acc[t] = __builtin_amdgcn_mfma_f32_16x16x32_bf16(
                        a1u, bfr[t][1], acc[t], 0, 0, 0);
                }
            }
            #pragma unroll
            for (int t = 0; t < 5; ++t)
                #pragma unroll
                for (int reg = 0; reg < 4; ++reg)
                    Dn[(kg * 4 + reg) * 84 + t * 16 + m] = acc[t][reg];

            // ---- issue raw A loads for group g+2 ----
            if (g + 2 < ngroups) {
                const int tg_n = dir ? (511 - ((g + 2) * 8 + tl))
                                     : ((g + 2) * 8 + tl);
                if constexpr (L0) {
                    const float* xr = (const float*)in_ +
                                      ((size_t)b_a * TT + tg_n) * 32 + kg * 8;
                    xraw0 = *(const float4*)xr;
                    xraw1 = *(const float4*)(xr + 4);
                } else {
                    size_t rowoff = ((size_t)b_a * TT + tg_n) * 24;
                    const unsigned short* p0 =
                        (kg < 3) ? (r0 + rowoff + 8 * kg) : (r1 + rowoff);
                    const unsigned short* p1 =
                        (kg == 0) ? (r1 + rowoff + 8) : (r1 + rowoff + 16);
                    a0r = *(const bf16x8*)p0;
                    a1r = *(const bf16x8*)p1;
                }
            }
        }

        // ---- 8 scan steps; h via LDS f16 rows of 32 (unmasked writes) ----
        #pragma unroll
        for (int s8 = 0; s8 < 8; ++s8) {
            const _Float16* hr = &hw[(s8 * 2 + bl) * 32];   // prev h (f16)
            uint4 hq0 = *(const uint4*)hr;          // f16 0..7
            uint4 hq1 = *(const uint4*)(hr + 8);    // f16 8..15
            uint4 hq2 = *(const uint4*)(hr + 16);   // f16 16..23
            unsigned hwd[12] = {hq0.x, hq0.y, hq0.z, hq0.w,
                                hq1.x, hq1.y, hq1.z, hq1.w,
                                hq2.x, hq2.y, hq2.z, hq2.w};
            // dual accumulators per gate: 6-deep chains
            float a0a = xgr[s8][0], a1a = xgr[s8][1], a2a = bh2;
            float a0b = 0.f, a1b = 0.f, a2b = 0.f;
            #pragma unroll
            for (int k = 0; k < 6; ++k) {
                f16x2 hv = asf16x2(hwd[k]);
                a0a = __builtin_amdgcn_fdot2(asf16x2(wrp[0][k]), hv, a0a, false);
                a1a = __builtin_amdgcn_fdot2(asf16x2(wrp[1][k]), hv, a1a, false);
                a2a = __builtin_amdgcn_fdot2(asf16x2(wrp[2][k]), hv, a2a, false);
            }
            #pragma unroll
            for (int k = 6; k < 12; ++k) {
                f16x2 hv = asf16x2(hwd[k]);
                a0b = __builtin_amdgcn_fdot2(asf16x2(wrp[0][k]), hv, a0b, false);
                a1b = __builtin_amdgcn_fdot2(asf16x2(wrp[1][k]), hv, a1b, false);
                a2b = __builtin_amdgcn_fdot2(asf16x2(wrp[2][k]), hv, a2b, false);
            }
            float r_ = sigm(a0a + a0b);
            float z_ = sigm(a1a + a1b);
            float n_ = tanh_(__builtin_fmaf(r_, a2a + a2b, xgr[s8][2]));
            float hnew = n_ + z_ * (hold - n_);
            hold = hnew;
            if constexpr (LAST) {
                int tg = dir ? (511 - (g * 8 + s8)) : (g * 8 + s8);
                if (u < 23 && tg == TT - 1)
                    lastbuf[bg * 48 + dir * 23 + u] = hnew;
            }
            wbar();
            hw[((s8 + 1) * 2 + bl) * 32 + u] = (_Float16)hnew;  // pads land in 24..31
            wbar();   // next step's reads stay after this write (in-order DS)
        }

        // ---- cooperative coalesced store of the 8-step block ----
        if constexpr (!LAST) {
            #pragma unroll
            for (int c = 0; c < 3; ++c) {
                f16x2 pf = asf16x2(*(const unsigned*)&hw[ldsoff[c]]);
                float lo = (float)pf[0];
                float hi = (cparr[c] == 11) ? 0.f : (float)pf[1];  // col 23 := 0
                unsigned pack = (unsigned)f2bf(lo) | ((unsigned)f2bf(hi) << 16);
                int tg = dir ? (511 - (g * 8 + sarr[c])) : (g * 8 + sarr[c]);
                *(unsigned*)(dstbase + (size_t)tg * 24 + 2 * cparr[c]) = pack;
            }
        }
        // carry h into row 0 for next group (disjoint from store-phase rows)
        hw[bl * 32 + u] = (_Float16)hold;
        wbar();
        cur ^= 1;
    }
}

__global__ __launch_bounds__(256) void fc_kernel(
    const float* __restrict__ last, const float* __restrict__ fcw,
    const float* __restrict__ fcb, const float* __restrict__ ostd,
    const float* __restrict__ omean, float* __restrict__ out)
{
    int idx = blockIdx.x * 256 + threadIdx.x;
    if (idx >= BB * NOUT) return;
    int b = idx >> 3, o = idx & 7;
    float acc = fcb[o];
    const float* lr = last + b * 48;
    const float* wr = fcw + o * 46;
    #pragma unroll
    for (int i = 0; i < 46; i++) acc += lr[i] * wr[i];
    out[idx] = acc * ostd[o] + omean[o];
}

extern "C" void kernel_launch(void* const* d_in, const int* in_sizes, int n_in,
                              void* d_out, int out_size, void* d_ws,
                              size_t ws_size, hipStream_t stream)
{
    const float* x     = (const float*)d_in[0];
    const float* fmean = (const float*)d_in[1];
    const float* fstd  = (const float*)d_in[2];
    const float* omean = (const float*)d_in[3];
    const float* ostd  = (const float*)d_in[4];
    const float* wih0  = (const float*)d_in[5];
    const float* whh0  = (const float*)d_in[6];
    const float* bih0  = (const float*)d_in[7];
    const float* bhh0  = (const float*)d_in[8];
    const float* wihr  = (const float*)d_in[9];
    const float* whhr  = (const float*)d_in[10];
    const float* bihr  = (const float*)d_in[11];
    const float* bhhr  = (const float*)d_in[12];
    const float* fcw   = (const float*)d_in[13];
    const float* fcb   = (const float*)d_in[14];

    char* ws = (char*)d_ws;
    const size_t bufBytes = 2 * DSTRIDE * sizeof(__hip_bfloat16);  // 96 MiB
    __hip_bfloat16* buf0 = (__hip_bfloat16*)ws;
    __hip_bfloat16* buf1 = (__hip_bfloat16*)(ws + bufBytes);
    float* lastb         = (float*)(ws + 2 * bufBytes);

    dim3 grid(BB / 8, 2);

    gru_mfma<true, false><<<grid, 256, 0, stream>>>(
        x, fmean, fstd, wih0, whh0, bih0, bhh0, buf0, nullptr);
    gru_mfma<false, false><<<grid, 256, 0, stream>>>(
        buf0, nullptr, nullptr, wihr + 0 * 2 * 69 * 46, whhr + 0 * 2 * 69 * 23,
        bihr + 0 * 2 * 69, bhhr + 0 * 2 * 69, buf1, nullptr);
    gru_mfma<false, true><<<grid, 256, 0, stream>>>(
        buf1, nullptr, nullptr, wihr + 1 * 2 * 69 * 46, whhr + 1 * 2 * 69 * 23,
        bihr + 1 * 2 * 69, bhhr + 1 * 2 * 69, nullptr, lastb);
    fc_kernel<<<(BB * NOUT + 255) / 256, 256, 0, stream>>>(lastb, fcw, fcb, ostd,
                                                           omean, (float*)d_out);
}